// Round 10
// baseline (57.298 us; speedup 1.0000x reference)
//
#include <hip/hip_runtime.h>
#include <hip/hip_bf16.h>
#include <stdint.h>

// Problem constants
#define BB 16
#define NPTS 100000
#define NBOX 64
#define KTOP 2048
#define THRF 0.2f            // (float)(8*0.01*2.5)
// band around 0.2^2 for exact-path fallback; fast path error bound ~5e-6
#define C_LO 0.039984f
#define C_HI 0.040016f

#define SLICES 16
#define SLICE_SPAN 6272      // 15*6272 + 5920 = 100000; all spans %4 == 0
#define SCAP 512             // per-slice candidate cap (expected ~143 +/- 12, 30 sigma)
#define LIST_CAP 4096        // per-batch cap (expected ~2278 +/- 47, 38 sigma)
#define CUT 0xC0000000u      // fmap(2.0f): candidates = scores >= 2.0

// Workspace (uint32 words). No zeroing needed: counts are plain-stored every launch.
#define CAND_OFF 0                       // BB*SLICES*SCAP candidate values
#define CNT_OFF  (BB * SLICES * SCAP)    // BB*SLICES raw counts (may exceed SCAP)

__device__ __forceinline__ uint32_t fmap(float f) {
    uint32_t b = __float_as_uint(f);
    return (b & 0x80000000u) ? ~b : (b | 0x80000000u);
}

// ---------- K1: full-machine candidate filter (scores >= 2.0), plain stores ----------
__global__ __launch_bounds__(256) void cand_k(const float* __restrict__ scores,
                                              uint32_t* __restrict__ ws) {
    __shared__ uint32_t buf[SCAP];
    __shared__ uint32_t lcnt;
    const int b = blockIdx.y, sl = blockIdx.x, tid = threadIdx.x;
    if (tid == 0) lcnt = 0;
    __syncthreads();
    const int start = sl * SLICE_SPAN;
    const int nf4 = min(SLICE_SPAN, NPTS - start) >> 2;
    const float4* sc4 = reinterpret_cast<const float4*>(scores + (size_t)b * NPTS + start);
    for (int i4 = tid; i4 < nf4; i4 += 256) {
        const float4 v = sc4[i4];
        const uint32_t u[4] = {fmap(v.x), fmap(v.y), fmap(v.z), fmap(v.w)};
#pragma unroll
        for (int j = 0; j < 4; ++j) {
            if (u[j] >= CUT) {  // ~2.3% of elements -> ~1.5 lanes/wave-instr
                const uint32_t pos = atomicAdd(&lcnt, 1u);
                if (pos < SCAP) buf[pos] = u[j];
            }
        }
    }
    __syncthreads();
    const uint32_t c = lcnt;
    uint32_t* dst = ws + CAND_OFF + ((size_t)(b * SLICES + sl)) * SCAP;
    const uint32_t cw = c < SCAP ? c : SCAP;
    for (uint32_t i = tid; i < cw; i += 256) dst[i] = buf[i];
    if (tid == 0) ws[CNT_OFF + b * SLICES + sl] = c;  // raw count (overflow-detectable)
}

// 256-thread suffix-sum pick: largest bin with suffix >= target. All threads call.
__device__ __forceinline__ void pick256(const uint32_t* __restrict__ hist,
                                        uint32_t* __restrict__ excl,
                                        int tid, int lane, uint32_t target,
                                        uint32_t* sBin, uint32_t* sKrem,
                                        uint32_t* sE, uint32_t* sTot, int wantE) {
    __syncthreads();  // hist ready
    if (tid < 64) {
        const uint32_t v0 = hist[4*tid], v1 = hist[4*tid+1], v2 = hist[4*tid+2], v3 = hist[4*tid+3];
        const uint32_t lt = v0 + v1 + v2 + v3;
        uint32_t x = lt;
#pragma unroll
        for (int off = 1; off < 64; off <<= 1) {
            const uint32_t y = __shfl_up(x, off);
            if (lane >= off) x += y;
        }
        const uint32_t ex = x - lt;
        excl[4*tid] = ex; excl[4*tid+1] = ex + v0;
        excl[4*tid+2] = ex + v0 + v1; excl[4*tid+3] = ex + v0 + v1 + v2;
        if (tid == 63) *sTot = x;
    }
    __syncthreads();
    {
        const uint32_t total = *sTot, lim = total - target;
        const uint32_t pe = excl[tid];
        const uint32_t pe1 = (tid == 255) ? total : excl[tid + 1];
        if (pe <= lim && pe1 > lim) {  // unique interval containing lim
            *sBin = (uint32_t)tid;
            *sKrem = target - (total - pe1);
            if (wantE) *sE = pe1 - pe;
        }
    }
    __syncthreads();
}

// ---------- exact (numpy-bit-identical) gt check for one point ----------
__device__ __noinline__ bool exact_gt(float px, float py, float pz,
                                      const float* __restrict__ C) {
    bool hit = false;
#pragma unroll 1
    for (int k = 0; k < NBOX; ++k) {
        float dx = px - C[3 * k + 0];
        float dy = py - C[3 * k + 1];
        float dz = pz - C[3 * k + 2];
        float d2 = __fadd_rn(__fadd_rn(__fmul_rn(dx, dx), __fmul_rn(dy, dy)),
                             __fmul_rn(dz, dz));
        if (__fsqrt_rn(d2) < THRF) hit = true;
    }
    return hit;
}

// ---------- K2: per-block redundant T-select prolog + gt mask + losses ----------
__global__ __launch_bounds__(256) void main_k(const float* __restrict__ scores,
                                              const float* __restrict__ points,
                                              const float* __restrict__ ctrs,
                                              const uint32_t* __restrict__ ws,
                                              float* __restrict__ out) {
    const int b = blockIdx.y, tid = threadIdx.x, w = tid >> 6, lane = tid & 63;
    __shared__ union { uint32_t h4[4][257]; uint32_t list[LIST_CAP]; } U;
    __shared__ uint32_t hist[256], excl[256];
    __shared__ uint32_t scnt[SLICES], soff[SLICES];
    __shared__ uint32_t wcnt[4];
    __shared__ uint32_t sBin, sKrem, sE, sTot, sIstar, sRun, sSpec, lcnt;

    const float* sc = scores + (size_t)b * NPTS;

    // ---- prolog: select T for this batch (all blocks of the batch, redundantly) ----
    if (tid < SLICES) scnt[tid] = ws[CNT_OFF + b * SLICES + tid];
    __syncthreads();
    if (tid == 0) {
        uint32_t tot = 0; bool ok = true;
        for (int s = 0; s < SLICES; ++s) {
            soff[s] = tot;
            const uint32_t c = scnt[s];
            if (c > SCAP) ok = false;
            tot += c;
        }
        sTot = tot;
        sSpec = (ok && tot >= KTOP && tot <= LIST_CAP) ? 1u : 0u;
        sKrem = KTOP;
        sIstar = NPTS;
        lcnt = 0;
    }
    __syncthreads();

    uint32_t cnt, prefix;
    int shift0;
    if (sSpec) {
        // gather ~2.3k candidates from L2 (9 KB/batch, shared across 98 blocks)
        cnt = sTot;
#pragma unroll 1
        for (int s = 0; s < SLICES; ++s) {
            const uint32_t c = scnt[s], o = soff[s];
            const uint32_t* src = ws + CAND_OFF + ((size_t)(b * SLICES + s)) * SCAP;
            for (uint32_t i = tid; i < c; i += 256) U.list[o + i] = src[i];
        }
        prefix = 0u;
        shift0 = 24;  // list spans bins [0xC0,0xFF]; start at MSB
    } else {
        // fallback (never on N(0,1) data): full hist + bin compact, this block only
        for (int i = tid; i < 4 * 257; i += 256) (&U.h4[0][0])[i] = 0;
        __syncthreads();
        const float4* sc4 = reinterpret_cast<const float4*>(sc);
        for (int i4 = tid; i4 < NPTS / 4; i4 += 256) {
            const float4 v = sc4[i4];
            atomicAdd(&U.h4[w][fmap(v.x) >> 24], 1u);
            atomicAdd(&U.h4[w][fmap(v.y) >> 24], 1u);
            atomicAdd(&U.h4[w][fmap(v.z) >> 24], 1u);
            atomicAdd(&U.h4[w][fmap(v.w) >> 24], 1u);
        }
        __syncthreads();
        hist[tid] = U.h4[0][tid] + U.h4[1][tid] + U.h4[2][tid] + U.h4[3][tid];
        pick256(hist, excl, tid, lane, KTOP, &sBin, &sKrem, &sE, &sTot, 0);
        const uint32_t beta = sBin;
        __syncthreads();  // h4 dead; list may be written now
        for (int i4 = tid; i4 < NPTS / 4; i4 += 256) {
            const float4 v = sc4[i4];
            const uint32_t u[4] = {fmap(v.x), fmap(v.y), fmap(v.z), fmap(v.w)};
#pragma unroll
            for (int j = 0; j < 4; ++j) {
                if ((u[j] >> 24) == beta) {
                    const uint32_t pos = atomicAdd(&lcnt, 1u);
                    if (pos < LIST_CAP) U.list[pos] = u[j];
                }
            }
        }
        __syncthreads();
        cnt = lcnt < LIST_CAP ? lcnt : LIST_CAP;
        prefix = beta << 24;
        shift0 = 16;
    }

    // radix passes over the candidate list
#pragma unroll 1
    for (int shift = shift0; shift >= 0; shift -= 8) {
        __syncthreads();      // list ready / previous pass done
        hist[tid] = 0;
        __syncthreads();
        const uint32_t hi8 = (shift < 24) ? (prefix >> (shift + 8)) : 0u;
        for (uint32_t i = tid; i < cnt; i += 256) {
            const uint32_t uu = U.list[i];
            const bool m = (shift == 24) || ((uu >> (shift + 8)) == hi8);
            if (m) atomicAdd(&hist[(uu >> shift) & 255u], 1u);
        }
        const uint32_t target = sKrem;
        pick256(hist, excl, tid, lane, target, &sBin, &sKrem, &sE, &sTot,
                shift == 0 ? 1 : 0);
        prefix |= sBin << shift;
    }

    const uint32_t R = sKrem, E = sE;
    const uint32_t tbits = (prefix & 0x80000000u) ? (prefix & 0x7fffffffu) : ~prefix;

    if (E != R) {
        // rare: find global index of the 0-based rank-R element equal to T
        const float T = __uint_as_float(tbits);
        if (tid == 0) sRun = 0;
        __syncthreads();
        for (int base = 0; base < NPTS; base += 256) {
            const uint32_t r0 = sRun;
            if (r0 > R) break;
            const int i = base + tid;
            const bool eq = (i < NPTS) && (sc[i] == T);
            const unsigned long long mask = __ballot(eq);
            if (lane == 0) wcnt[w] = (uint32_t)__popcll(mask);
            __syncthreads();
            uint32_t before = 0, total = 0;
#pragma unroll
            for (int ww = 0; ww < 4; ++ww) {
                const uint32_t c = wcnt[ww];
                if (ww < w) before += c;
                total += c;
            }
            if (eq) {
                const uint32_t rank = r0 + before +
                    (uint32_t)__popcll(mask & ((1ull << lane) - 1ull));
                if (rank == R) sIstar = (uint32_t)i;
            }
            __syncthreads();
            if (tid == 0) sRun = r0 + total;
            __syncthreads();
        }
    }
    __syncthreads();
    const float T = __uint_as_float(tbits);
    const uint32_t Istar = sIstar;

    // ---- main body: gt mask + prune mask + losses (no barriers below) ----
    const int p0 = blockIdx.x * 1024 + tid * 4;
    if (p0 >= NPTS) return;

    const float* P = points + ((size_t)b * NPTS + p0) * 3;
    const float4 a = *reinterpret_cast<const float4*>(P);
    const float4 c4 = *reinterpret_cast<const float4*>(P + 4);
    const float4 e = *reinterpret_cast<const float4*>(P + 8);
    const float px[4] = {a.x, a.w, c4.z, e.y};
    const float py[4] = {a.y, c4.x, c4.w, e.z};
    const float pz[4] = {a.z, c4.y, e.x, e.w};
    // d^2 = p.p + (c.c - 2 p.c); min commutes with +p.p (per-point constant)
    float m2[4] = {1e30f, 1e30f, 1e30f, 1e30f};

    const float* C = ctrs + b * NBOX * 3;
#pragma unroll 16
    for (int k = 0; k < NBOX; ++k) {
        const float cx = C[3 * k + 0];
        const float cy = C[3 * k + 1];
        const float cz = C[3 * k + 2];
        const float cc = fmaf(cx, cx, fmaf(cy, cy, cz * cz));
        const float m2x = -2.0f * cx, m2y = -2.0f * cy, m2z = -2.0f * cz;
#pragma unroll
        for (int j = 0; j < 4; ++j) {
            const float t = fmaf(m2x, px[j], fmaf(m2y, py[j], fmaf(m2z, pz[j], cc)));
            m2[j] = fminf(m2[j], t);
        }
    }

    const float4 sv = *reinterpret_cast<const float4*>(sc + p0);
    const float s[4] = {sv.x, sv.y, sv.z, sv.w};
    float pr[4], ls[4];
#pragma unroll
    for (int j = 0; j < 4; ++j) {
        const float pp = fmaf(px[j], px[j], fmaf(py[j], py[j], pz[j] * pz[j]));
        const float m = pp + m2[j];
        bool gt;
        if (m < C_LO) gt = true;
        else if (m >= C_HI) gt = false;
        else gt = exact_gt(px[j], py[j], pz[j], C);  // rare boundary band
        const bool sm = (s[j] > T) || (s[j] == T && (uint32_t)(p0 + j) < Istar);
        pr[j] = (gt || sm) ? 1.0f : 0.0f;
        const float x = gt ? -s[j] : s[j];
        // fast softplus: tolerance is bf16-level (9.4e-2); hw exp/log err ~1e-6
        ls[j] = fmaxf(x, 0.0f) + __logf(1.0f + __expf(-fabsf(s[j])));
    }
    float* o0 = out + (size_t)b * NPTS + p0;
    float* o1 = out + (size_t)BB * NPTS + (size_t)b * NPTS + p0;
    *reinterpret_cast<float4*>(o0) = make_float4(pr[0], pr[1], pr[2], pr[3]);
    *reinterpret_cast<float4*>(o1) = make_float4(ls[0], ls[1], ls[2], ls[3]);
}

extern "C" void kernel_launch(void* const* d_in, const int* in_sizes, int n_in,
                              void* d_out, int out_size, void* d_ws, size_t ws_size,
                              hipStream_t stream) {
    const float* scores = (const float*)d_in[0];
    const float* points = (const float*)d_in[1];
    const float* ctrs   = (const float*)d_in[2];
    float* out = (float*)d_out;
    uint32_t* ws = (uint32_t*)d_ws;

    const dim3 gridC(SLICES, BB);   // 16 x 16 = 256 blocks
    cand_k<<<gridC, 256, 0, stream>>>(scores, ws);
    const dim3 gridP(98, BB);
    main_k<<<gridP, 256, 0, stream>>>(scores, points, ctrs, ws, out);
}

// Round 11
// 46.331 us; speedup vs baseline: 1.2367x; 1.2367x over previous
//
#include <hip/hip_runtime.h>
#include <hip/hip_bf16.h>
#include <stdint.h>

// Problem constants
#define BB 16
#define NPTS 100000
#define NBOX 64
#define KTOP 2048
#define THRF 0.2f            // (float)(8*0.01*2.5)
// band around 0.2^2 for exact-path fallback; fast path error bound ~5e-6
#define C_LO 0.039984f
#define C_HI 0.040016f

#define SLICES 16
#define SLICE_SPAN 6272      // 15*6272 + 5920 = 100000; all spans %4 == 0
#define SCAP 512             // per-slice candidate cap (expected ~143 +/- 12, 30 sigma)
#define LIST_CAP 4096        // per-batch cap (expected ~2278 +/- 47, 38 sigma)
#define CUT 0xC0000000u      // fmap(2.0f): candidates = scores >= 2.0

// Workspace (uint32 words). No zeroing needed: counts are plain-stored every launch.
#define CAND_OFF 0                       // BB*SLICES*SCAP candidate values
#define CNT_OFF  (BB * SLICES * SCAP)    // BB*SLICES raw counts (may exceed SCAP)

__device__ __forceinline__ uint32_t fmap(float f) {
    uint32_t b = __float_as_uint(f);
    return (b & 0x80000000u) ? ~b : (b | 0x80000000u);
}

// ---------- K1: full-machine candidate filter (scores >= 2.0), plain stores ----------
__global__ __launch_bounds__(256) void cand_k(const float* __restrict__ scores,
                                              uint32_t* __restrict__ ws) {
    __shared__ uint32_t buf[SCAP];
    __shared__ uint32_t lcnt;
    const int b = blockIdx.y, sl = blockIdx.x, tid = threadIdx.x;
    if (tid == 0) lcnt = 0;
    __syncthreads();
    const int start = sl * SLICE_SPAN;
    const int nf4 = min(SLICE_SPAN, NPTS - start) >> 2;
    const float4* sc4 = reinterpret_cast<const float4*>(scores + (size_t)b * NPTS + start);
    for (int i4 = tid; i4 < nf4; i4 += 256) {
        const float4 v = sc4[i4];
        const uint32_t u[4] = {fmap(v.x), fmap(v.y), fmap(v.z), fmap(v.w)};
#pragma unroll
        for (int j = 0; j < 4; ++j) {
            if (u[j] >= CUT) {  // ~2.3% of elements -> ~1.5 lanes/wave-instr
                const uint32_t pos = atomicAdd(&lcnt, 1u);
                if (pos < SCAP) buf[pos] = u[j];
            }
        }
    }
    __syncthreads();
    const uint32_t c = lcnt;
    uint32_t* dst = ws + CAND_OFF + ((size_t)(b * SLICES + sl)) * SCAP;
    const uint32_t cw = c < SCAP ? c : SCAP;
    for (uint32_t i = tid; i < cw; i += 256) dst[i] = buf[i];
    if (tid == 0) ws[CNT_OFF + b * SLICES + sl] = c;  // raw count (overflow-detectable)
}

// 256-thread suffix-sum pick: largest bin with suffix >= target. All threads call.
__device__ __forceinline__ void pick256(const uint32_t* __restrict__ hist,
                                        uint32_t* __restrict__ excl,
                                        int tid, int lane, uint32_t target,
                                        uint32_t* sBin, uint32_t* sKrem,
                                        uint32_t* sE, uint32_t* sTot, int wantE) {
    __syncthreads();  // hist ready
    if (tid < 64) {
        const uint32_t v0 = hist[4*tid], v1 = hist[4*tid+1], v2 = hist[4*tid+2], v3 = hist[4*tid+3];
        const uint32_t lt = v0 + v1 + v2 + v3;
        uint32_t x = lt;
#pragma unroll
        for (int off = 1; off < 64; off <<= 1) {
            const uint32_t y = __shfl_up(x, off);
            if (lane >= off) x += y;
        }
        const uint32_t ex = x - lt;
        excl[4*tid] = ex; excl[4*tid+1] = ex + v0;
        excl[4*tid+2] = ex + v0 + v1; excl[4*tid+3] = ex + v0 + v1 + v2;
        if (tid == 63) *sTot = x;
    }
    __syncthreads();
    {
        const uint32_t total = *sTot, lim = total - target;
        const uint32_t pe = excl[tid];
        const uint32_t pe1 = (tid == 255) ? total : excl[tid + 1];
        if (pe <= lim && pe1 > lim) {  // unique interval containing lim
            *sBin = (uint32_t)tid;
            *sKrem = target - (total - pe1);
            if (wantE) *sE = pe1 - pe;
        }
    }
    __syncthreads();
}

// ---------- exact (numpy-bit-identical) gt check for one point ----------
__device__ __noinline__ bool exact_gt(float px, float py, float pz,
                                      const float* __restrict__ C) {
    bool hit = false;
#pragma unroll 1
    for (int k = 0; k < NBOX; ++k) {
        float dx = px - C[3 * k + 0];
        float dy = py - C[3 * k + 1];
        float dz = pz - C[3 * k + 2];
        float d2 = __fadd_rn(__fadd_rn(__fmul_rn(dx, dx), __fmul_rn(dy, dy)),
                             __fmul_rn(dz, dz));
        if (__fsqrt_rn(d2) < THRF) hit = true;
    }
    return hit;
}

// ---------- K2: per-block T-select prolog (conflict-free) + gt mask + losses ----------
__global__ __launch_bounds__(256) void main_k(const float* __restrict__ scores,
                                              const float* __restrict__ points,
                                              const float* __restrict__ ctrs,
                                              const uint32_t* __restrict__ ws,
                                              float* __restrict__ out) {
    const int b = blockIdx.y, tid = threadIdx.x, w = tid >> 6, lane = tid & 63;
    __shared__ uint32_t list[LIST_CAP];      // 16 KB
    __shared__ uint32_t h4[4][257];          // lane-spread hist copies (4.1 KB)
    __shared__ uint32_t hist[256], excl[256];
    __shared__ uint32_t scnt[SLICES], soff[SLICES];
    __shared__ uint32_t wcnt[4];
    __shared__ uint32_t sBin, sKrem, sE, sTot, sIstar, sRun, sSpec, sUni, lcnt;

    const float* sc = scores + (size_t)b * NPTS;

    // ---- prolog: select T for this batch (each block, redundant but cheap) ----
    if (tid < SLICES) scnt[tid] = ws[CNT_OFF + b * SLICES + tid];
    __syncthreads();
    if (tid == 0) {
        uint32_t tot = 0; bool ok = true;
        for (int s = 0; s < SLICES; ++s) {
            soff[s] = tot;
            const uint32_t c = scnt[s];
            if (c > SCAP) ok = false;
            tot += c;
        }
        sTot = tot;
        sSpec = (ok && tot >= KTOP && tot <= LIST_CAP) ? 1u : 0u;
        sKrem = KTOP;
        sIstar = NPTS;
        lcnt = 0;
        sUni = 1u;
    }
    __syncthreads();

    uint32_t cnt, prefix = 0u;
    int shift0;
    if (sSpec) {
        // gather ~2.3k candidates from L2 (9 KB/batch, shared across 98 blocks)
        cnt = sTot;
#pragma unroll 1
        for (int s = 0; s < SLICES; ++s) {
            const uint32_t c = scnt[s], o = soff[s];
            const uint32_t* src = ws + CAND_OFF + ((size_t)(b * SLICES + s)) * SCAP;
            for (uint32_t i = tid; i < c; i += 256) list[o + i] = src[i];
        }
        __syncthreads();
        // MSB-byte uniformity check: skip the (degenerate) shift=24 pass if uniform.
        const uint32_t b0 = list[0] >> 24;
        bool uni = true;
        for (uint32_t i = tid; i < cnt; i += 256) uni &= ((list[i] >> 24) == b0);
        if (!uni) atomicAnd(&sUni, 0u);
        __syncthreads();
        if (sUni) { prefix = b0 << 24; shift0 = 16; }  // all mass in bin b0 -> krem = KTOP
        else      { prefix = 0u;       shift0 = 24; }
    } else {
        // fallback (never on N(0,1) data): full hist + bin compact, this block only
        for (int i = tid; i < 4 * 257; i += 256) (&h4[0][0])[i] = 0;
        __syncthreads();
        const float4* sc4 = reinterpret_cast<const float4*>(sc);
        for (int i4 = tid; i4 < NPTS / 4; i4 += 256) {
            const float4 v = sc4[i4];
            atomicAdd(&h4[w][fmap(v.x) >> 24], 1u);
            atomicAdd(&h4[w][fmap(v.y) >> 24], 1u);
            atomicAdd(&h4[w][fmap(v.z) >> 24], 1u);
            atomicAdd(&h4[w][fmap(v.w) >> 24], 1u);
        }
        __syncthreads();
        hist[tid] = h4[0][tid] + h4[1][tid] + h4[2][tid] + h4[3][tid];
        pick256(hist, excl, tid, lane, KTOP, &sBin, &sKrem, &sE, &sTot, 0);
        const uint32_t beta = sBin;
        for (int i4 = tid; i4 < NPTS / 4; i4 += 256) {
            const float4 v = sc4[i4];
            const uint32_t u[4] = {fmap(v.x), fmap(v.y), fmap(v.z), fmap(v.w)};
#pragma unroll
            for (int j = 0; j < 4; ++j) {
                if ((u[j] >> 24) == beta) {
                    const uint32_t pos = atomicAdd(&lcnt, 1u);
                    if (pos < LIST_CAP) list[pos] = u[j];
                }
            }
        }
        __syncthreads();
        cnt = lcnt < LIST_CAP ? lcnt : LIST_CAP;
        prefix = beta << 24;
        shift0 = 16;
    }

    // radix passes over the candidate list (lane-spread histograms, conflict-light)
#pragma unroll 1
    for (int shift = shift0; shift >= 0; shift -= 8) {
        for (int i = tid; i < 4 * 257; i += 256) (&h4[0][0])[i] = 0;
        __syncthreads();
        const uint32_t hi8 = (shift < 24) ? (prefix >> (shift + 8)) : 0u;
        uint32_t* mh = h4[lane & 3];
        for (uint32_t i = tid; i < cnt; i += 256) {
            const uint32_t uu = list[i];
            const bool m = (shift == 24) || ((uu >> (shift + 8)) == hi8);
            if (m) atomicAdd(&mh[(uu >> shift) & 255u], 1u);
        }
        __syncthreads();
        hist[tid] = h4[0][tid] + h4[1][tid] + h4[2][tid] + h4[3][tid];
        const uint32_t target = sKrem;
        pick256(hist, excl, tid, lane, target, &sBin, &sKrem, &sE, &sTot,
                shift == 0 ? 1 : 0);
        prefix |= sBin << shift;
    }

    const uint32_t R = sKrem, E = sE;
    const uint32_t tbits = (prefix & 0x80000000u) ? (prefix & 0x7fffffffu) : ~prefix;

    if (E != R) {
        // rare: find global index of the 0-based rank-R element equal to T
        const float T = __uint_as_float(tbits);
        if (tid == 0) sRun = 0;
        __syncthreads();
        for (int base = 0; base < NPTS; base += 256) {
            const uint32_t r0 = sRun;
            if (r0 > R) break;
            const int i = base + tid;
            const bool eq = (i < NPTS) && (sc[i] == T);
            const unsigned long long mask = __ballot(eq);
            if (lane == 0) wcnt[w] = (uint32_t)__popcll(mask);
            __syncthreads();
            uint32_t before = 0, total = 0;
#pragma unroll
            for (int ww = 0; ww < 4; ++ww) {
                const uint32_t c = wcnt[ww];
                if (ww < w) before += c;
                total += c;
            }
            if (eq) {
                const uint32_t rank = r0 + before +
                    (uint32_t)__popcll(mask & ((1ull << lane) - 1ull));
                if (rank == R) sIstar = (uint32_t)i;
            }
            __syncthreads();
            if (tid == 0) sRun = r0 + total;
            __syncthreads();
        }
    }
    __syncthreads();
    const float T = __uint_as_float(tbits);
    const uint32_t Istar = sIstar;

    // ---- main body: gt mask + prune mask + losses (no barriers below) ----
    const int p0 = blockIdx.x * 1024 + tid * 4;
    if (p0 >= NPTS) return;

    const float* P = points + ((size_t)b * NPTS + p0) * 3;
    const float4 a = *reinterpret_cast<const float4*>(P);
    const float4 c4 = *reinterpret_cast<const float4*>(P + 4);
    const float4 e = *reinterpret_cast<const float4*>(P + 8);
    const float px[4] = {a.x, a.w, c4.z, e.y};
    const float py[4] = {a.y, c4.x, c4.w, e.z};
    const float pz[4] = {a.z, c4.y, e.x, e.w};
    // d^2 = p.p + (c.c - 2 p.c); min commutes with +p.p (per-point constant)
    float m2[4] = {1e30f, 1e30f, 1e30f, 1e30f};

    const float* C = ctrs + b * NBOX * 3;
#pragma unroll 16
    for (int k = 0; k < NBOX; ++k) {
        const float cx = C[3 * k + 0];
        const float cy = C[3 * k + 1];
        const float cz = C[3 * k + 2];
        const float cc = fmaf(cx, cx, fmaf(cy, cy, cz * cz));
        const float m2x = -2.0f * cx, m2y = -2.0f * cy, m2z = -2.0f * cz;
#pragma unroll
        for (int j = 0; j < 4; ++j) {
            const float t = fmaf(m2x, px[j], fmaf(m2y, py[j], fmaf(m2z, pz[j], cc)));
            m2[j] = fminf(m2[j], t);
        }
    }

    const float4 sv = *reinterpret_cast<const float4*>(sc + p0);
    const float s[4] = {sv.x, sv.y, sv.z, sv.w};
    float pr[4], ls[4];
#pragma unroll
    for (int j = 0; j < 4; ++j) {
        const float pp = fmaf(px[j], px[j], fmaf(py[j], py[j], pz[j] * pz[j]));
        const float m = pp + m2[j];
        bool gt;
        if (m < C_LO) gt = true;
        else if (m >= C_HI) gt = false;
        else gt = exact_gt(px[j], py[j], pz[j], C);  // rare boundary band
        const bool sm = (s[j] > T) || (s[j] == T && (uint32_t)(p0 + j) < Istar);
        pr[j] = (gt || sm) ? 1.0f : 0.0f;
        const float x = gt ? -s[j] : s[j];
        // fast softplus: tolerance is bf16-level (9.4e-2); hw exp/log err ~1e-6
        ls[j] = fmaxf(x, 0.0f) + __logf(1.0f + __expf(-fabsf(s[j])));
    }
    float* o0 = out + (size_t)b * NPTS + p0;
    float* o1 = out + (size_t)BB * NPTS + (size_t)b * NPTS + p0;
    *reinterpret_cast<float4*>(o0) = make_float4(pr[0], pr[1], pr[2], pr[3]);
    *reinterpret_cast<float4*>(o1) = make_float4(ls[0], ls[1], ls[2], ls[3]);
}

extern "C" void kernel_launch(void* const* d_in, const int* in_sizes, int n_in,
                              void* d_out, int out_size, void* d_ws, size_t ws_size,
                              hipStream_t stream) {
    const float* scores = (const float*)d_in[0];
    const float* points = (const float*)d_in[1];
    const float* ctrs   = (const float*)d_in[2];
    float* out = (float*)d_out;
    uint32_t* ws = (uint32_t*)d_ws;

    const dim3 gridC(SLICES, BB);   // 16 x 16 = 256 blocks
    cand_k<<<gridC, 256, 0, stream>>>(scores, ws);
    const dim3 gridP(98, BB);
    main_k<<<gridP, 256, 0, stream>>>(scores, points, ctrs, ws, out);
}